// Round 4
// baseline (5597.989 us; speedup 1.0000x reference)
//
#include <hip/hip_runtime.h>
#include <hip/hip_bf16.h>
#include <cfloat>

using bf16 = __hip_bfloat16;

constexpr int Bb = 8, Nn = 4096, Kk = 20;
constexpr int BN = Bb * Nn;                     // 32768
constexpr int Mrows = BN * Kk;                  // 655360
constexpr float EPSf = 1e-5f;

static __device__ __forceinline__ float b2f(bf16 v){ return __bfloat162float(v); }
static __device__ __forceinline__ bf16 f2b(float v){ return __float2bfloat16(v); }
static __device__ __forceinline__ unsigned short f2bu(float v){
  union { bf16 b; unsigned short u; } cv; cv.b = __float2bfloat16(v); return cv.u;
}
static __device__ __forceinline__ float ldf(bf16 v){ return b2f(v); }
static __device__ __forceinline__ float ldf(float v){ return v; }

// ---------------- zero workspace region ----------------
__global__ void zero_kernel(float* __restrict__ p, int n){
  int i = blockIdx.x*256 + threadIdx.x;
  if (i < n) p[i] = 0.f;
}

// ---------------- KNN phase A: per-point top-20 over a j-stripe (4 stripes) ----------------
// grid: b(8) x chunk(16) x stripe(4) = 512 blocks of 256 threads.
__global__ __launch_bounds__(256) void knnA_kernel(const float* __restrict__ x,
                                                   float* __restrict__ pv, int* __restrict__ pi){
#pragma clang fp contract(off)
  __shared__ float4 p4[1024];
  int blk = blockIdx.x;
  int stripe = blk & 3;
  int chunk  = (blk >> 2) & 15;
  int b      = blk >> 6;
  const float* xb = x + b*3*Nn;
  int j0 = stripe*1024;
  for (int u = threadIdx.x; u < 1024; u += 256){
    int j = j0 + u;
    float a0 = xb[j];
    float a1 = xb[Nn + j];
    float a2 = xb[2*Nn + j];
    float s = a0*a0; s = s + a1*a1; s = s + a2*a2;   // xx = ((x^2)+(y^2))+(z^2)
    p4[u] = make_float4(a0, a1, a2, s);
  }
  __syncthreads();
  int i = chunk*256 + threadIdx.x;
  float xi = xb[i], yi = xb[Nn+i], zi = xb[2*Nn+i];
  float ni = xi*xi; ni = ni + yi*yi; ni = ni + zi*zi;
  float mni = -ni;
  float tv[Kk]; int ti[Kk];
  #pragma unroll
  for (int s=0;s<Kk;++s){ tv[s] = -FLT_MAX; ti[s] = 0; }
  for (int u=0; u<1024; ++u){
    float4 p = p4[u];
    float dot = xi*p.x; dot = dot + yi*p.y; dot = dot + zi*p.z;
    float inner = -2.0f*dot;
    float nd = mni - inner; nd = nd - p.w;            // (-xx_i - inner) - xx_j
    if (nd > tv[Kk-1]){
      #pragma unroll
      for (int s=Kk-1; s>=1; --s){
        bool cs = nd > tv[s];
        bool cp = nd > tv[s-1];
        tv[s] = cs ? (cp ? tv[s-1] : nd) : tv[s];
        ti[s] = cs ? (cp ? ti[s-1] : (j0+u)) : ti[s];
      }
      if (nd > tv[0]){ tv[0] = nd; ti[0] = j0+u; }
    }
  }
  long long base = ((long long)(b*Nn + i)*4 + stripe)*Kk;
  #pragma unroll
  for (int s=0;s<Kk;++s){ pv[base+s] = tv[s]; pi[base+s] = ti[s]; }
}

// ---------------- KNN phase B: merge the four stripe lists ----------------
__global__ __launch_bounds__(256) void knnB_kernel(const float* __restrict__ pv,
                                                   const int* __restrict__ pi,
                                                   int* __restrict__ idx){
  int p = blockIdx.x*256 + threadIdx.x;
  if (p >= BN) return;
  long long base = (long long)p*4*Kk;
  float av[Kk]; int ai[Kk];
  #pragma unroll
  for (int s=0;s<Kk;++s){ av[s]=pv[base+s]; ai[s]=pi[base+s]; }
  // stripes processed in ascending-j order; strict > keeps smaller-index-wins ties
  for (int t=Kk; t<4*Kk; ++t){
    float nd = pv[base+t]; int j = pi[base+t];
    if (nd > av[Kk-1]){
      #pragma unroll
      for (int s=Kk-1;s>=1;--s){
        bool cs = nd > av[s];
        bool cp = nd > av[s-1];
        av[s] = cs ? (cp?av[s-1]:nd) : av[s];
        ai[s] = cs ? (cp?ai[s-1]:j) : ai[s];
      }
      if (nd > av[0]){ av[0]=nd; ai[0]=j; }
    }
  }
  #pragma unroll
  for (int s=0;s<Kk;++s) idx[(long long)p*Kk+s] = ai[s];
}

// ---------------- layer-1 feature stats: sum(f) and f^T f (6x6) ----------------
__global__ __launch_bounds__(256) void gramf_kernel(const float* __restrict__ x,
                                                    const int* __restrict__ idx,
                                                    float* __restrict__ part){
  float acc[36]; float s6[6];
  #pragma unroll
  for (int a=0;a<36;++a) acc[a]=0.f;
  #pragma unroll
  for (int a=0;a<6;++a) s6[a]=0.f;
  for (long long row = blockIdx.x*256 + threadIdx.x; row < Mrows; row += (long long)gridDim.x*256){
    int bn = (int)(row / Kk);
    int b = bn >> 12, n = bn & 4095;
    int j = idx[row];
    const float* xb = x + b*3*Nn;
    float f[6];
    f[0]=xb[j];  f[1]=xb[Nn+j];  f[2]=xb[2*Nn+j];
    f[3]=xb[n];  f[4]=xb[Nn+n];  f[5]=xb[2*Nn+n];
    #pragma unroll
    for (int a=0;a<6;++a){
      s6[a] += f[a];
      #pragma unroll
      for (int c=0;c<6;++c) acc[a*6+c] = fmaf(f[a], f[c], acc[a*6+c]);
    }
  }
  __shared__ float red[256];
  for (int v=0; v<42; ++v){
    red[threadIdx.x] = (v<36)? acc[v] : s6[v-36];
    __syncthreads();
    for (int s=128; s>0; s>>=1){
      if (threadIdx.x < s) red[threadIdx.x] += red[threadIdx.x+s];
      __syncthreads();
    }
    if (threadIdx.x==0) part[blockIdx.x*48 + v] = red[0];
    __syncthreads();
  }
}

__global__ void reducef_kernel(const float* __restrict__ part, float* __restrict__ Gf,
                               float* __restrict__ sumf){
  int t = threadIdx.x;
  if (t < 42){
    float s = 0.f;
    for (int i=0;i<256;++i) s += part[i*48 + t];
    if (t<36) Gf[t]=s; else sumf[t-36]=s;
  }
}

// ---------------- Gram: G = H^T H, 64x64 tiles ----------------
template<int CIN, typename T>
__global__ __launch_bounds__(256) void gram_kernel(const T* __restrict__ H, int M,
                                                   float* __restrict__ G){
  constexpr int Tt = CIN/64;
  int tile = blockIdx.x % (Tt*Tt);
  int chunk = blockIdx.x / (Tt*Tt);
  int nchunks = gridDim.x / (Tt*Tt);
  int tr = tile / Tt, tc = tile % Tt;
  __shared__ float Aw[16][64];
  __shared__ float Bw[16][64];
  int rpc = (M + nchunks - 1)/nchunks;
  int r0 = chunk*rpc; int r1 = min(M, r0+rpc);
  int tx = threadIdx.x & 15, ty = threadIdx.x >> 4;
  float acc[4][4] = {};
  for (int rb=r0; rb<r1; rb+=16){
    int nr = min(16, r1-rb);
    for (int u=threadIdx.x; u<1024; u+=256){
      int rr = u >> 6, cc = u & 63;
      float av=0.f, bv=0.f;
      if (rr < nr){
        const T* hp = H + (size_t)(rb+rr)*CIN;
        av = ldf(hp[tr*64+cc]);
        bv = ldf(hp[tc*64+cc]);
      }
      Aw[rr][cc]=av; Bw[rr][cc]=bv;
    }
    __syncthreads();
    for (int r=0;r<nr;++r){
      float4 af = *(const float4*)&Aw[r][ty*4];
      float4 bf = *(const float4*)&Bw[r][tx*4];
      float a[4] = {af.x, af.y, af.z, af.w};
      float bq[4] = {bf.x, bf.y, bf.z, bf.w};
      #pragma unroll
      for (int u=0;u<4;++u)
        #pragma unroll
        for (int v=0;v<4;++v) acc[u][v] = fmaf(a[u], bq[v], acc[u][v]);
    }
    __syncthreads();
  }
  #pragma unroll
  for (int u=0;u<4;++u)
    #pragma unroll
    for (int v=0;v<4;++v)
      atomicAdd(&G[(size_t)(tr*64+ty*4+u)*CIN + (tc*64+tx*4+v)], acc[u][v]);
}

// ---------------- column sums of H ----------------
template<int CIN, typename T>
__global__ __launch_bounds__(256) void colsum_kernel(const T* __restrict__ H, int M,
                                                     float* __restrict__ sumh){
  int rpb = (M + gridDim.x - 1)/gridDim.x;
  int r0 = blockIdx.x*rpb, r1 = min(M, r0+rpb);
  if constexpr (CIN <= 256){
    constexpr int RP = 256/CIN;
    int c = threadIdx.x % CIN;
    int sub = threadIdx.x / CIN;
    float a = 0.f;
    for (int r=r0+sub; r<r1; r+=RP) a += ldf(H[(size_t)r*CIN + c]);
    atomicAdd(&sumh[c], a);
  } else {
    float a0=0.f, a1=0.f;
    for (int r=r0;r<r1;++r){
      a0 += ldf(H[(size_t)r*CIN + threadIdx.x]);
      a1 += ldf(H[(size_t)r*CIN + threadIdx.x + 256]);
    }
    atomicAdd(&sumh[threadIdx.x], a0);
    atomicAdd(&sumh[threadIdx.x+256], a1);
  }
}

// ---------------- P = G @ W ----------------
__global__ void kP_kernel(const float* __restrict__ G, const float* __restrict__ Wf,
                          float* __restrict__ P, int Cin, int Cout){
  int id = blockIdx.x*256 + threadIdx.x;
  if (id >= Cin*Cout) return;
  int i = id / Cout, j = id - i*Cout;
  float s = 0.f;
  for (int k=0;k<Cin;++k) s = fmaf(G[(size_t)i*Cin+k], Wf[(size_t)k*Cout+j], s);
  P[id] = s;
}

// ---------------- scale/shift from Gram-derived BN stats ----------------
__global__ void kFinal_kernel(const float* __restrict__ P, const float* __restrict__ sumh,
                              const float* __restrict__ Wf, const float* __restrict__ g,
                              const float* __restrict__ bb, float* __restrict__ scale,
                              float* __restrict__ shift, int Cin, int Cout, float invM){
  int j = blockIdx.x*256 + threadIdx.x;
  if (j >= Cout) return;
  float mean=0.f, e2=0.f;
  for (int i=0;i<Cin;++i){
    float w = Wf[(size_t)i*Cout + j];
    mean = fmaf(sumh[i], w, mean);
    e2   = fmaf(w, P[(size_t)i*Cout + j], e2);
  }
  mean *= invM; e2 *= invM;
  float var = e2 - mean*mean;
  float inv = rsqrtf(var + EPSf);
  float sc = g[j]*inv;
  scale[j]=sc;
  shift[j]=bb[j] - mean*sc;
}

// ---------------- layer-2 stats: on-the-fly H1 -> Gram2(64x64) + colsum2 ----------------
__global__ __launch_bounds__(256) void stats2_kernel(const float* __restrict__ x,
    const int* __restrict__ idx, const float* __restrict__ W1f,
    const float* __restrict__ sc1v, const float* __restrict__ sh1v,
    float* __restrict__ G2, float* __restrict__ sum2){
  __shared__ float W1s[6][64];
  __shared__ float fsh[16][6];
  __shared__ float Aw[16][64];
  __shared__ float scs[64], shs[64];
  int tid = threadIdx.x;
  for (int u=tid; u<384; u+=256) W1s[u/64][u%64] = W1f[u];
  if (tid < 64){ scs[tid]=sc1v[tid]; shs[tid]=sh1v[tid]; }
  __syncthreads();
  int rpc = (Mrows + gridDim.x - 1)/gridDim.x;
  int r0 = blockIdx.x*rpc, r1 = min(Mrows, r0+rpc);
  int ty = tid >> 4, tx = tid & 15;
  int myc = tid & 63;
  float acc[4][4] = {};
  float cs = 0.f;
  for (int rb=r0; rb<r1; rb+=16){
    if (tid < 16){
      int row = rb + tid;
      float f0=0,f1=0,f2=0,f3=0,f4=0,f5=0;
      if (row < r1){
        int bn = row / Kk;
        int b = bn >> 12, n = bn & 4095;
        int j = idx[row];
        const float* xb = x + b*3*Nn;
        f0=xb[j]; f1=xb[Nn+j]; f2=xb[2*Nn+j];
        f3=xb[n]; f4=xb[Nn+n]; f5=xb[2*Nn+n];
      }
      fsh[tid][0]=f0; fsh[tid][1]=f1; fsh[tid][2]=f2;
      fsh[tid][3]=f3; fsh[tid][4]=f4; fsh[tid][5]=f5;
    }
    __syncthreads();
    #pragma unroll
    for (int k=0;k<4;++k){
      int rr = (tid>>6) + k*4;
      float y = 0.f;
      #pragma unroll
      for (int i=0;i<6;++i) y = fmaf(fsh[rr][i], W1s[i][myc], y);
      float v = fmaxf(fmaf(y, scs[myc], shs[myc]), 0.f);
      if (rb + rr >= r1) v = 0.f;
      Aw[rr][myc] = v;
      cs += v;
    }
    __syncthreads();
    for (int r=0;r<16;++r){
      float4 af = *(const float4*)&Aw[r][ty*4];
      float4 bf = *(const float4*)&Aw[r][tx*4];
      float a[4] = {af.x, af.y, af.z, af.w};
      float bq[4] = {bf.x, bf.y, bf.z, bf.w};
      #pragma unroll
      for (int u=0;u<4;++u)
        #pragma unroll
        for (int v=0;v<4;++v) acc[u][v]=fmaf(a[u],bq[v],acc[u][v]);
    }
    __syncthreads();
  }
  #pragma unroll
  for (int u=0;u<4;++u)
    #pragma unroll
    for (int v=0;v<4;++v)
      atomicAdd(&G2[(size_t)(ty*4+u)*64 + tx*4+v], acc[u][v]);
  atomicAdd(&sum2[myc], cs);
}

// ---------------- fused layers 1+2: gather->H1->x1, H1@W2 -> H2(bf16) + x2 ----------------
__global__ __launch_bounds__(64) void fl12_kernel(const float* __restrict__ x,
    const int* __restrict__ idx, const float* __restrict__ W1f,
    const float* __restrict__ sc1v, const float* __restrict__ sh1v,
    const float* __restrict__ W2f, const float* __restrict__ sc2v,
    const float* __restrict__ sh2v, bf16* __restrict__ H2, bf16* __restrict__ cat){
  __shared__ float fsh[Kk][6];
  __shared__ float h1[Kk][64];
  __shared__ float mm[4][64];
  int bn = blockIdx.x, b = bn>>12, n = bn & 4095;
  int tid = threadIdx.x;
  if (tid < Kk){
    int j = idx[(size_t)bn*Kk + tid];
    const float* xb = x + b*3*Nn;
    fsh[tid][0]=xb[j]; fsh[tid][1]=xb[Nn+j]; fsh[tid][2]=xb[2*Nn+j];
    fsh[tid][3]=xb[n]; fsh[tid][4]=xb[Nn+n]; fsh[tid][5]=xb[2*Nn+n];
  }
  __syncthreads();
  {
    float sc=sc1v[tid], sh=sh1v[tid];
    float w[6];
    #pragma unroll
    for (int i=0;i<6;++i) w[i]=W1f[i*64+tid];
    float mx = 0.f;
    #pragma unroll
    for (int r=0;r<Kk;++r){
      float y=0.f;
      #pragma unroll
      for (int i=0;i<6;++i) y = fmaf(fsh[r][i], w[i], y);
      float v = fmaxf(fmaf(y,sc,sh),0.f);
      h1[r][tid]=v;
      mx = fmaxf(mx,v);
    }
    cat[(size_t)bn*512 + tid] = f2b(mx);
  }
  __syncthreads();
  int q = tid >> 4, c0 = (tid & 15)*4;
  float acc[5][4]={};
  for (int i0=0;i0<64;i0+=4){
    float hv[5][4];
    #pragma unroll
    for (int l=0;l<5;++l){
      float4 t4 = *(const float4*)&h1[q*5+l][i0];
      hv[l][0]=t4.x; hv[l][1]=t4.y; hv[l][2]=t4.z; hv[l][3]=t4.w;
    }
    #pragma unroll
    for (int ii=0;ii<4;++ii){
      const float* wp = W2f + (i0+ii)*64 + c0;
      float w0=wp[0],w1=wp[1],w2=wp[2],w3=wp[3];
      #pragma unroll
      for (int l=0;l<5;++l){
        float hvv=hv[l][ii];
        acc[l][0]=fmaf(hvv,w0,acc[l][0]);
        acc[l][1]=fmaf(hvv,w1,acc[l][1]);
        acc[l][2]=fmaf(hvv,w2,acc[l][2]);
        acc[l][3]=fmaf(hvv,w3,acc[l][3]);
      }
    }
  }
  float sc[4],sh[4];
  #pragma unroll
  for (int cb=0;cb<4;++cb){ sc[cb]=sc2v[c0+cb]; sh[cb]=sh2v[c0+cb]; }
  float mx[4]={0,0,0,0};
  #pragma unroll
  for (int l=0;l<5;++l){
    unsigned short us[4];
    #pragma unroll
    for (int cb=0;cb<4;++cb){
      float v=fmaxf(fmaf(acc[l][cb],sc[cb],sh[cb]),0.f);
      mx[cb]=fmaxf(mx[cb],v);
      us[cb]=f2bu(v);
    }
    uint2 v2; v2.x = us[0]|((unsigned)us[1]<<16); v2.y=us[2]|((unsigned)us[3]<<16);
    *(uint2*)(H2 + ((size_t)bn*Kk + q*5+l)*64 + c0) = v2;
  }
  #pragma unroll
  for (int cb=0;cb<4;++cb) mm[q][c0+cb]=mx[cb];
  __syncthreads();
  {
    float M0 = fmaxf(fmaxf(mm[0][tid],mm[1][tid]),fmaxf(mm[2][tid],mm[3][tid]));
    cat[(size_t)bn*512 + 64 + tid] = f2b(M0);
  }
}

// ---------------- layer-4 stats: on-the-fly H3 -> Gram4(128x128) + colsum4 ----------------
__global__ __launch_bounds__(256) void stats4_kernel(const bf16* __restrict__ H2,
    const float* __restrict__ W3f, const float* __restrict__ sc3v, const float* __restrict__ sh3v,
    float* __restrict__ G4, float* __restrict__ sum4){
  __shared__ float W3s[64][128];
  __shared__ float h2s[16][64];
  __shared__ float h3s[16][128];
  __shared__ float scs[128], shs[128];
  int tid = threadIdx.x;
  for (int u=tid; u<64*128; u+=256) W3s[u>>7][u&127]=W3f[u];
  if (tid<128){ scs[tid]=sc3v[tid]; shs[tid]=sh3v[tid]; }
  __syncthreads();
  int rpc=(Mrows+gridDim.x-1)/gridDim.x;
  int r0=blockIdx.x*rpc, r1=min(Mrows,r0+rpc);
  int ty=tid>>4, tx=tid&15;             // gram 8x8 tile
  int rr2=tid>>5, cg=tid&31;            // produce: rows {2*rr2,2*rr2+1}, cols cg*4..+3
  float acc[8][8]={};
  float cs[4]={0.f,0.f,0.f,0.f};
  float sca[4], sha[4];
  #pragma unroll
  for (int k=0;k<4;++k){ sca[k]=sc3v[cg*4+k]; sha[k]=sh3v[cg*4+k]; }
  for (int rb=r0; rb<r1; rb+=16){
    for (int u=tid; u<1024; u+=256){
      int rr=u>>6, cc=u&63;
      float v=0.f;
      int row=rb+rr;
      if (row<r1) v=b2f(H2[(size_t)row*64+cc]);
      h2s[rr][cc]=v;
    }
    __syncthreads();
    // produce h3s: 2 rows x 4 cols per thread, i-ascending accumulation
    {
      float y0[4]={0,0,0,0}, y1[4]={0,0,0,0};
      int ra = rr2*2, rbb = rr2*2+1;
      for (int i=0;i<64;++i){
        float4 w = *(const float4*)&W3s[i][cg*4];
        float ha = h2s[ra][i], hb = h2s[rbb][i];
        y0[0]=fmaf(ha,w.x,y0[0]); y0[1]=fmaf(ha,w.y,y0[1]);
        y0[2]=fmaf(ha,w.z,y0[2]); y0[3]=fmaf(ha,w.w,y0[3]);
        y1[0]=fmaf(hb,w.x,y1[0]); y1[1]=fmaf(hb,w.y,y1[1]);
        y1[2]=fmaf(hb,w.z,y1[2]); y1[3]=fmaf(hb,w.w,y1[3]);
      }
      bool oka = (rb+ra < r1), okb = (rb+rbb < r1);
      float va[4], vb[4];
      #pragma unroll
      for (int k=0;k<4;++k){
        float v0 = fmaxf(fmaf(y0[k],sca[k],sha[k]),0.f);
        float v1 = fmaxf(fmaf(y1[k],sca[k],sha[k]),0.f);
        va[k] = oka ? v0 : 0.f;
        vb[k] = okb ? v1 : 0.f;
        cs[k] += va[k]; cs[k] += vb[k];
      }
      *(float4*)&h3s[ra][cg*4]  = make_float4(va[0],va[1],va[2],va[3]);
      *(float4*)&h3s[rbb][cg*4] = make_float4(vb[0],vb[1],vb[2],vb[3]);
    }
    __syncthreads();
    for (int r=0;r<16;++r){
      float4 a0 = *(const float4*)&h3s[r][ty*8];
      float4 a1 = *(const float4*)&h3s[r][ty*8+4];
      float4 b0 = *(const float4*)&h3s[r][tx*8];
      float4 b1 = *(const float4*)&h3s[r][tx*8+4];
      float a[8] = {a0.x,a0.y,a0.z,a0.w,a1.x,a1.y,a1.z,a1.w};
      float bq[8] = {b0.x,b0.y,b0.z,b0.w,b1.x,b1.y,b1.z,b1.w};
      #pragma unroll
      for (int u=0;u<8;++u)
        #pragma unroll
        for (int v=0;v<8;++v) acc[u][v]=fmaf(a[u],bq[v],acc[u][v]);
    }
    __syncthreads();
  }
  #pragma unroll
  for (int u=0;u<8;++u)
    #pragma unroll
    for (int v=0;v<8;++v)
      atomicAdd(&G4[(size_t)(ty*8+u)*128 + tx*8+v], acc[u][v]);
  #pragma unroll
  for (int k=0;k<4;++k) atomicAdd(&sum4[cg*4+k], cs[k]);
}

// ---------------- fused layers 3+4: 4 points/block. H2->H3->x3, H3@W4->x4 ----------------
__global__ __launch_bounds__(512) void fl34_kernel(const bf16* __restrict__ H2,
    const float* __restrict__ W3f, const float* __restrict__ sc3v, const float* __restrict__ sh3v,
    const float* __restrict__ W4f, const float* __restrict__ sc4v, const float* __restrict__ sh4v,
    bf16* __restrict__ cat){
  __shared__ float h2s[4][Kk][64];      // 20 KB
  __shared__ float h3s[4][Kk][128];     // 40 KB
  __shared__ float w4s[16][256];        // 16 KB, aliased as mm[4][4][256] after K-loop
  int tid = threadIdx.x;
  int bn0 = blockIdx.x*4;
  int pt = tid >> 7, tid2 = tid & 127;
  for (int u=tid; u<4*Kk*64; u+=512){
    int p = u / 1280, rem = u - p*1280;
    h2s[p][rem>>6][rem&63] = b2f(H2[((size_t)(bn0+p)*Kk + (rem>>6))*64 + (rem&63)]);
  }
  __syncthreads();
  // stage 1: H3 column tid2 for point pt, all 20 rows (i-ascending)
  {
    int c = tid2;
    float y[Kk];
    #pragma unroll
    for (int r=0;r<Kk;++r) y[r]=0.f;
    for (int i=0;i<64;++i){
      float w = W3f[i*128 + c];
      #pragma unroll
      for (int r=0;r<Kk;++r) y[r]=fmaf(h2s[pt][r][i], w, y[r]);
    }
    float sc=sc3v[c], sh=sh3v[c];
    float mx=0.f;
    #pragma unroll
    for (int r=0;r<Kk;++r){
      float v=fmaxf(fmaf(y[r],sc,sh),0.f);
      h3s[pt][r][c]=v;
      mx=fmaxf(mx,v);
    }
    cat[(size_t)(bn0+pt)*512 + 128 + c] = f2b(mx);
  }
  __syncthreads();
  // stage 2: Y4 = H3 @ W4; per point: 4 rowgroups(5) x 32 colgroups(8 strided)
  int q = tid2 >> 5, cbase = tid2 & 31;
  float acc[5][8]={};
  for (int i0=0;i0<128;i0+=16){
    for (int u=tid;u<4096;u+=512) w4s[u>>8][u&255]=W4f[(size_t)(i0+(u>>8))*256+(u&255)];
    __syncthreads();
    for (int ii=0;ii<16;++ii){
      float w[8];
      #pragma unroll
      for (int cb=0;cb<8;++cb) w[cb]=w4s[ii][cbase + cb*32];
      float hv[5];
      #pragma unroll
      for (int l=0;l<5;++l) hv[l]=h3s[pt][q*5+l][i0+ii];
      #pragma unroll
      for (int l=0;l<5;++l)
        #pragma unroll
        for (int cb=0;cb<8;++cb) acc[l][cb]=fmaf(hv[l],w[cb],acc[l][cb]);
    }
    __syncthreads();
  }
  float sc[8],sh[8];
  #pragma unroll
  for (int cb=0;cb<8;++cb){ sc[cb]=sc4v[cbase+cb*32]; sh[cb]=sh4v[cbase+cb*32]; }
  float mx[8];
  #pragma unroll
  for (int cb=0;cb<8;++cb) mx[cb]=0.f;
  #pragma unroll
  for (int l=0;l<5;++l)
    #pragma unroll
    for (int cb=0;cb<8;++cb){
      float v=fmaxf(fmaf(acc[l][cb],sc[cb],sh[cb]),0.f);
      mx[cb]=fmaxf(mx[cb],v);
    }
  float* mmf = &w4s[0][0];   // [4][4][256] alias (w4s dead after last sync)
  #pragma unroll
  for (int cb=0;cb<8;++cb) mmf[((pt*4+q)<<8) + cbase + cb*32] = mx[cb];
  __syncthreads();
  for (int u=tid; u<1024; u+=512){
    int p = u >> 8, c = u & 255;
    float M0 = fmaxf(fmaxf(mmf[((p*4+0)<<8)+c], mmf[((p*4+1)<<8)+c]),
                     fmaxf(mmf[((p*4+2)<<8)+c], mmf[((p*4+3)<<8)+c]));
    cat[(size_t)(bn0+p)*512 + 256 + c] = f2b(M0);
  }
}

// ---------------- layer 5: cat(bf16,512) @ W5, BN+ReLU, fp32 transposed store ----------------
__global__ __launch_bounds__(256) void l5_kernel(const bf16* __restrict__ cat,
                                                const float* __restrict__ Wf,
                                                const float* __restrict__ scale,
                                                const float* __restrict__ shift,
                                                float* __restrict__ out){
  __shared__ float cr[8][512];
  __shared__ float ob[8][512];
  int tid = threadIdx.x;
  int bn0 = blockIdx.x*8;
  for (int u=tid; u<8*512; u+=256) cr[u>>9][u&511] = b2f(cat[(size_t)bn0*512 + u]);
  __syncthreads();
  int rp = tid >> 6, cg = tid & 63, c0 = cg*8;
  int ra = rp*2, rb = rp*2+1;
  float acc[2][8] = {};
  for (int i=0;i<512;++i){
    float h0 = cr[ra][i], h1 = cr[rb][i];
    const float* wp = Wf + (size_t)i*512 + c0;
    float4 wa = *(const float4*)wp;
    float4 wb = *(const float4*)(wp+4);
    float w[8] = {wa.x,wa.y,wa.z,wa.w,wb.x,wb.y,wb.z,wb.w};
    #pragma unroll
    for (int k=0;k<8;++k){
      acc[0][k] = fmaf(h0, w[k], acc[0][k]);
      acc[1][k] = fmaf(h1, w[k], acc[1][k]);
    }
  }
  float sc[8], sh[8];
  #pragma unroll
  for (int k=0;k<8;++k){ sc[k]=scale[c0+k]; sh[k]=shift[c0+k]; }
  #pragma unroll
  for (int k=0;k<8;++k){
    ob[ra][c0+k] = fmaxf(fmaf(acc[0][k], sc[k], sh[k]), 0.f);
    ob[rb][c0+k] = fmaxf(fmaf(acc[1][k], sc[k], sh[k]), 0.f);
  }
  __syncthreads();
  int b = bn0 >> 12, n0 = bn0 & 4095;
  for (int u=tid; u<512; u+=256){
    float4 v0 = make_float4(ob[0][u], ob[1][u], ob[2][u], ob[3][u]);
    float4 v1 = make_float4(ob[4][u], ob[5][u], ob[6][u], ob[7][u]);
    float* op = out + ((size_t)b*512 + u)*4096 + n0;
    *(float4*)(op)   = v0;
    *(float4*)(op+4) = v1;
  }
}

extern "C" void kernel_launch(void* const* d_in, const int* in_sizes, int n_in,
                              void* d_out, int out_size, void* d_ws, size_t ws_size,
                              hipStream_t stream){
  const float* x   = (const float*)d_in[0];
  const float* W1f = (const float*)d_in[1];
  const float* W2f = (const float*)d_in[2];
  const float* W3f = (const float*)d_in[3];
  const float* W4f = (const float*)d_in[4];
  const float* W5f = (const float*)d_in[5];
  const float* g1=(const float*)d_in[6],  *b1=(const float*)d_in[7];
  const float* g2=(const float*)d_in[8],  *b2=(const float*)d_in[9];
  const float* g3=(const float*)d_in[10], *b3=(const float*)d_in[11];
  const float* g4=(const float*)d_in[12], *b4=(const float*)d_in[13];
  const float* g5=(const float*)d_in[14], *b5=(const float*)d_in[15];
  float* out = (float*)d_out;

  char* w = (char*)d_ws;
  size_t off = 0;
  auto alloc = [&](size_t bytes)->void*{
    void* p = w + off;
    off = (off + bytes + 255) & ~(size_t)255;
    return p;
  };

  int*  idxb = (int*) alloc((size_t)BN*Kk*4);          // 2.6 MB
  bf16* H2   = (bf16*)alloc((size_t)Mrows*64*2);       // 84 MB
  bf16* catb = (bf16*)alloc((size_t)BN*512*2);         // 33.6 MB
  // KNN scratch aliases H2 (H2 first written by fl12, after knnB is done)
  float* pv  = (float*)H2;                             // 10.5 MB
  int*   pib = (int*)((char*)H2 + (size_t)BN*4*Kk*4);  // 10.5 MB

  size_t statsStart = off;
  float* partf=(float*)alloc(256*48*4);
  float* Gf=(float*)alloc(36*4);
  float* sumf=(float*)alloc(8*4);
  float* G2=(float*)alloc(4096*4);   float* sum2=(float*)alloc(64*4);
  float* G3=(float*)alloc(4096*4);   float* sum3=(float*)alloc(64*4);
  float* G4=(float*)alloc(16384*4);  float* sum4=(float*)alloc(128*4);
  float* G5=(float*)alloc(262144*4); float* sum5=(float*)alloc(512*4);
  float* P1=(float*)alloc(384*4);
  float* P2=(float*)alloc(4096*4);
  float* P3=(float*)alloc(8192*4);
  float* P4=(float*)alloc(32768*4);
  float* P5=(float*)alloc(262144*4);
  float* sc1=(float*)alloc(64*4);   float* sh1=(float*)alloc(64*4);
  float* sc2=(float*)alloc(64*4);   float* sh2=(float*)alloc(64*4);
  float* sc3=(float*)alloc(128*4);  float* sh3=(float*)alloc(128*4);
  float* sc4=(float*)alloc(256*4);  float* sh4=(float*)alloc(256*4);
  float* sc5=(float*)alloc(512*4);  float* sh5=(float*)alloc(512*4);
  size_t statsEnd = off;

  int statsFloats = (int)((statsEnd - statsStart)/4);
  zero_kernel<<<(statsFloats+255)/256,256,0,stream>>>((float*)(w+statsStart), statsFloats);

  knnA_kernel<<<512,256,0,stream>>>(x, pv, pib);
  knnB_kernel<<<BN/256,256,0,stream>>>(pv, pib, idxb);

  const float invM  = 1.0f/(float)Mrows;
  const float invM5 = 1.0f/(float)BN;

  // layer 1 stats
  gramf_kernel<<<256,256,0,stream>>>(x, idxb, partf);
  reducef_kernel<<<1,64,0,stream>>>(partf, Gf, sumf);
  kP_kernel<<<2,256,0,stream>>>(Gf, W1f, P1, 6, 64);
  kFinal_kernel<<<1,256,0,stream>>>(P1, sumf, W1f, g1, b1, sc1, sh1, 6, 64, invM);

  // layer 2 stats (on-the-fly H1)
  stats2_kernel<<<2048,256,0,stream>>>(x, idxb, W1f, sc1, sh1, G2, sum2);
  kP_kernel<<<16,256,0,stream>>>(G2, W2f, P2, 64, 64);
  kFinal_kernel<<<1,256,0,stream>>>(P2, sum2, W2f, g2, b2, sc2, sh2, 64, 64, invM);

  // apply layers 1+2
  fl12_kernel<<<BN,64,0,stream>>>(x, idxb, W1f, sc1, sh1, W2f, sc2, sh2, H2, catb);

  // layer 3 stats from H2
  colsum_kernel<64,bf16><<<512,256,0,stream>>>(H2, Mrows, sum3);
  gram_kernel<64,bf16><<<2048,256,0,stream>>>(H2, Mrows, G3);
  kP_kernel<<<32,256,0,stream>>>(G3, W3f, P3, 64, 128);
  kFinal_kernel<<<1,256,0,stream>>>(P3, sum3, W3f, g3, b3, sc3, sh3, 64, 128, invM);

  // layer 4 stats (on-the-fly H3)
  stats4_kernel<<<1536,256,0,stream>>>(H2, W3f, sc3, sh3, G4, sum4);
  kP_kernel<<<128,256,0,stream>>>(G4, W4f, P4, 128, 256);
  kFinal_kernel<<<1,256,0,stream>>>(P4, sum4, W4f, g4, b4, sc4, sh4, 128, 256, invM);

  // apply layers 3+4 (4 points per block)
  fl34_kernel<<<BN/4,512,0,stream>>>(H2, W3f, sc3, sh3, W4f, sc4, sh4, catb);

  // layer 5
  colsum_kernel<512,bf16><<<512,256,0,stream>>>(catb, BN, sum5);
  gram_kernel<512,bf16><<<2048,256,0,stream>>>(catb, BN, G5);
  kP_kernel<<<1024,256,0,stream>>>(G5, W5f, P5, 512, 512);
  kFinal_kernel<<<2,256,0,stream>>>(P5, sum5, W5f, g5, b5, sc5, sh5, 512, 512, invM5);
  l5_kernel<<<BN/8,256,0,stream>>>(catb, W5f, sc5, sh5, out);
}